// Round 1
// baseline (417.149 us; speedup 1.0000x reference)
//
#include <hip/hip_runtime.h>
#include <hip/hip_bf16.h>

#define N_NODES 8192
#define FIN 16
#define HD 64
#define E_EDGES 131072
#define S_SEQ 4
#define ROWS 76   // 12 adv + 64 val1
#define NH (N_NODES*HD)   // 524288

__device__ __forceinline__ float dot4(const float4 a, const float4 b) {
    return a.x*b.x + a.y*b.y + a.z*b.z + a.w*b.w;
}

// ---------------- K1: fold edge-MLP into R/Rb, pack GRU weights, zero headacc ----
__global__ __launch_bounds__(256) void k_pre(
        const float* __restrict__ w1, const float* __restrict__ b1,
        const float* __restrict__ W2, const float* __restrict__ b2,
        const float* __restrict__ Wih, const float* __restrict__ Whh,
        float* __restrict__ R, float* __restrict__ Rb,
        float* __restrict__ W4ih, float* __restrict__ W4hh,
        float* __restrict__ headacc) {
    int t = threadIdx.x;
    __shared__ float cw[64], cbs[64];
    if (t < 64) {
        float w = w1[t];
        bool pos = w > 0.f;
        cw[t] = pos ? w : 0.f;
        cbs[t] = pos ? b1[t] : 0.f;   // == 0 for these inputs (b1 = 0)
    }
    __syncthreads();
    for (int i = t; i < 1024; i += 256) {
        float r = 0.f, rb = b2[i];
        for (int j = 0; j < 64; ++j) {
            float w = W2[i*64 + j];
            r  += cw[j]  * w;
            rb += cbs[j] * w;
        }
        R[i] = r; Rb[i] = rb;
    }
    // pack W[gate*64+h][k] -> W4[((kb*3+gate)*64+h)*4 + c], k = kb*4+c
    for (int i = t; i < 12288; i += 256) {
        int kb = i / 768;
        int rem = i % 768;
        int gate = rem / 256;
        int rem2 = rem % 256;
        int h = rem2 / 4;
        int c = rem2 % 4;
        int src = (gate*64 + h)*64 + kb*4 + c;
        W4ih[i] = Wih[src];
        W4hh[i] = Whh[src];
    }
    for (int i = t; i < ROWS*4; i += 256) headacc[i] = 0.f;
}

// ---------------- K2: per-node precompute S1 = x0@R, S2 = x0@Rb, zero agg -------
__global__ __launch_bounds__(256) void k_node(
        const float* __restrict__ x, const float* __restrict__ R,
        const float* __restrict__ Rb, float* __restrict__ S1,
        float* __restrict__ S2, float* __restrict__ agg) {
    int idx = blockIdx.x*256 + threadIdx.x;    // v*64 + h, over N*H
    int h = idx & 63, v = idx >> 6;
    const float* xv = x + v*FIN;               // s = 0 slice only (matches ref)
    float s1 = 0.f, s2 = 0.f;
#pragma unroll
    for (int f = 0; f < FIN; ++f) {
        float xf = xv[f];
        s1 += xf * R[f*64 + h];
        s2 += xf * Rb[f*64 + h];
    }
    S1[idx] = s1; S2[idx] = s2; agg[idx] = 0.f;
}

// ---------------- K3: edge scatter: agg[dst] += a*S1[src] + S2[src] -------------
__global__ __launch_bounds__(256) void k_edge(
        const int* __restrict__ edge, const float* __restrict__ attr,
        const float* __restrict__ S1, const float* __restrict__ S2,
        float* __restrict__ agg) {
    int idx = blockIdx.x*256 + threadIdx.x;    // [0, E*64)
    int h = idx & 63, e = idx >> 6;
    int src = edge[e];
    int dst = edge[E_EDGES + e];
    float a = attr[e];
    float val = a * S1[src*64 + h] + S2[src*64 + h];
    atomicAdd(&agg[dst*64 + h], val);
}

// ---------------- K4: full 4-step GRU, one kernel, weights in LDS ---------------
__global__ __launch_bounds__(512) void k_gru(
        const float* __restrict__ x, const float* __restrict__ agg,
        const float* __restrict__ h0, const float* __restrict__ rootW,
        const float* __restrict__ convb, const float* __restrict__ bih,
        const float* __restrict__ bhh, const float* __restrict__ W4ih,
        const float* __restrict__ W4hh, float* __restrict__ YS) {
    __shared__ float4 wih[3072];               // 48 KB
    __shared__ float4 whh[3072];               // 48 KB
    __shared__ __align__(16) float xt[32][64]; // 8 KB
    __shared__ __align__(16) float hp[32][64]; // 8 KB
    __shared__ float xraw[32][16];             // 2 KB   (total 114 KB <= 160 KB)
    int tid = threadIdx.x;
    int h = tid & 63, g = tid >> 6;            // g in 0..7, wave-private group
    int v0 = blockIdx.x * 32;

    for (int i = tid; i < 3072; i += 512) {
        wih[i] = ((const float4*)W4ih)[i];
        whh[i] = ((const float4*)W4hh)[i];
    }
    float rw[16];
#pragma unroll
    for (int f = 0; f < 16; ++f) rw[f] = rootW[f*64 + h];
    float cbv = convb[h];
    float br_i = bih[h], bz_i = bih[64+h], bn_i = bih[128+h];
    float br_h = bhh[h], bz_h = bhh[64+h], bn_h = bhh[128+h];
    __syncthreads();

    // init hidden state from h0 (wave-private rows of hp)
#pragma unroll
    for (int n = 0; n < 4; ++n) {
        int node = g*4 + n;
        hp[node][h] = h0[(v0 + node)*64 + h];
    }

    for (int s = 0; s < 4; ++s) {
        // stage raw x for this step; thread layout keeps each wave writing its own rows
        {
            int i = tid >> 4, f = tid & 15;    // wave w writes nodes 4w..4w+3
            xraw[i][f] = x[((s*N_NODES) + v0 + i)*FIN + f];
        }
        // xt = relu(x@rootW + conv_b (+ agg at s==0))
#pragma unroll
        for (int n = 0; n < 4; ++n) {
            int node = g*4 + n;
            float acc = cbv;
#pragma unroll
            for (int f = 0; f < 16; ++f) acc += rw[f] * xraw[node][f];
            if (s == 0) acc += agg[(v0 + node)*64 + h];
            xt[node][h] = fmaxf(acc, 0.f);
        }
        // gates
        float ir[4] = {0,0,0,0}, iz[4] = {0,0,0,0}, in_[4] = {0,0,0,0};
        float hr[4] = {0,0,0,0}, hz[4] = {0,0,0,0}, hn[4] = {0,0,0,0};
        for (int kb = 0; kb < 16; ++kb) {
            float4 wr = wih[(kb*3+0)*64 + h];
            float4 wz = wih[(kb*3+1)*64 + h];
            float4 wn = wih[(kb*3+2)*64 + h];
            float4 ur = whh[(kb*3+0)*64 + h];
            float4 uz = whh[(kb*3+1)*64 + h];
            float4 un = whh[(kb*3+2)*64 + h];
#pragma unroll
            for (int n = 0; n < 4; ++n) {
                int node = g*4 + n;
                const float4 xv = *(const float4*)&xt[node][kb*4];
                const float4 hv = *(const float4*)&hp[node][kb*4];
                ir[n] += dot4(wr, xv);  iz[n] += dot4(wz, xv);  in_[n] += dot4(wn, xv);
                hr[n] += dot4(ur, hv);  hz[n] += dot4(uz, hv);  hn[n] += dot4(un, hv);
            }
        }
#pragma unroll
        for (int n = 0; n < 4; ++n) {
            int node = g*4 + n;
            float hprev = hp[node][h];
            float r = 1.f / (1.f + __expf(-(ir[n] + br_i + hr[n] + br_h)));
            float z = 1.f / (1.f + __expf(-(iz[n] + bz_i + hz[n] + bz_h)));
            float ng = tanhf(in_[n] + bn_i + r * (hn[n] + bn_h));
            float hnew = (1.f - z) * ng + z * hprev;
            hp[node][h] = hnew;
            YS[(s*N_NODES + v0 + node)*64 + h] = hnew;
        }
    }
}

// ---------------- K5: big head GEMV (76 rows x 524288) for all 4 steps ----------
__global__ __launch_bounds__(256) void k_heads(
        const float* __restrict__ YS, const float* __restrict__ advW,
        const float* __restrict__ v1W, float* __restrict__ headacc) {
    int lane = threadIdx.x & 63, w = threadIdx.x >> 6;
    int c0 = blockIdx.x << 10;                 // 1024-wide K chunk per block
    float4 y[4][4];
#pragma unroll
    for (int s = 0; s < 4; ++s)
#pragma unroll
        for (int i = 0; i < 4; ++i)
            y[s][i] = *(const float4*)&YS[s*NH + c0 + i*256 + lane*4];
    for (int j = 0; j < 19; ++j) {
        int r = w*19 + j;                      // rows 0..75
        const float* Wr = (r < 12) ? (advW + (size_t)r*NH) : (v1W + (size_t)(r-12)*NH);
        Wr += c0;
        float a0 = 0.f, a1 = 0.f, a2 = 0.f, a3 = 0.f;
#pragma unroll
        for (int i = 0; i < 4; ++i) {
            float4 wv = *(const float4*)&Wr[i*256 + lane*4];
            a0 += dot4(wv, y[0][i]);
            a1 += dot4(wv, y[1][i]);
            a2 += dot4(wv, y[2][i]);
            a3 += dot4(wv, y[3][i]);
        }
#pragma unroll
        for (int off = 32; off > 0; off >>= 1) {
            a0 += __shfl_down(a0, off, 64);
            a1 += __shfl_down(a1, off, 64);
            a2 += __shfl_down(a2, off, 64);
            a3 += __shfl_down(a3, off, 64);
        }
        if (lane == 0) {
            atomicAdd(&headacc[r*4 + 0], a0);
            atomicAdd(&headacc[r*4 + 1], a1);
            atomicAdd(&headacc[r*4 + 2], a2);
            atomicAdd(&headacc[r*4 + 3], a3);
        }
    }
}

// ---------------- K6: tiny tail: val2, val3, dueling combine --------------------
__global__ __launch_bounds__(256) void k_final(
        const float* __restrict__ headacc, const float* __restrict__ advb,
        const float* __restrict__ v1b, const float* __restrict__ W2v,
        const float* __restrict__ b2v, const float* __restrict__ W3v,
        const float* __restrict__ b3v, float* __restrict__ out) {
    __shared__ float val1[4][64];
    __shared__ float val2[4][64];
    __shared__ float advs[4][12];
    __shared__ float vs[4];
    int t = threadIdx.x;
    int s = t >> 6, j = t & 63;
    val1[s][j] = fmaxf(headacc[(12 + j)*4 + s] + v1b[j], 0.f);
    if (t < 48) {
        int ss = t / 12, a = t % 12;
        advs[ss][a] = fmaxf(headacc[a*4 + ss] + advb[a], 0.f);
    }
    __syncthreads();
    {
        float acc = b2v[j];
        for (int k = 0; k < 64; ++k) acc += W2v[j*64 + k] * val1[s][k];
        val2[s][j] = fmaxf(acc, 0.f);
    }
    __syncthreads();
    if (t < 4) {
        float acc = b3v[0];
        for (int k = 0; k < 64; ++k) acc += W3v[k] * val2[t][k];
        vs[t] = acc;
    }
    __syncthreads();
    if (t < 48) {
        int ss = t / 12, ga = t % 12;
        int grp = ga / 3;
        float m = (advs[ss][grp*3+0] + advs[ss][grp*3+1] + advs[ss][grp*3+2]) * (1.f/3.f);
        out[t] = vs[ss] + advs[ss][ga] - m;
    }
}

extern "C" void kernel_launch(void* const* d_in, const int* in_sizes, int n_in,
                              void* d_out, int out_size, void* d_ws, size_t ws_size,
                              hipStream_t stream) {
    const float* x     = (const float*)d_in[0];
    const int*   edge  = (const int*)  d_in[1];
    const float* attr  = (const float*)d_in[2];
    const float* h0    = (const float*)d_in[3];
    const float* w1    = (const float*)d_in[4];
    const float* b1    = (const float*)d_in[5];
    const float* W2    = (const float*)d_in[6];
    const float* b2    = (const float*)d_in[7];
    const float* rootW = (const float*)d_in[8];
    const float* convb = (const float*)d_in[9];
    const float* Wih   = (const float*)d_in[10];
    const float* Whh   = (const float*)d_in[11];
    const float* bih   = (const float*)d_in[12];
    const float* bhh   = (const float*)d_in[13];
    const float* advW  = (const float*)d_in[14];
    const float* advb  = (const float*)d_in[15];
    const float* v1W   = (const float*)d_in[16];
    const float* v1b   = (const float*)d_in[17];
    const float* v2W   = (const float*)d_in[18];
    const float* v2b   = (const float*)d_in[19];
    const float* v3W   = (const float*)d_in[20];
    const float* v3b   = (const float*)d_in[21];

    float* ws = (float*)d_ws;
    float* R       = ws;                 // 1024
    float* Rb      = ws + 1024;          // 1024
    float* S1      = ws + 2048;          // 524288
    float* S2      = ws + 526336;        // 524288
    float* agg     = ws + 1050624;       // 524288
    float* YS      = ws + 1574912;       // 2097152
    float* W4ih    = ws + 3672064;       // 12288
    float* W4hh    = ws + 3684352;       // 12288
    float* headacc = ws + 3696640;       // 304

    k_pre  <<<1,     256, 0, stream>>>(w1, b1, W2, b2, Wih, Whh, R, Rb, W4ih, W4hh, headacc);
    k_node <<<2048,  256, 0, stream>>>(x, R, Rb, S1, S2, agg);
    k_edge <<<32768, 256, 0, stream>>>(edge, attr, S1, S2, agg);
    k_gru  <<<256,   512, 0, stream>>>(x, agg, h0, rootW, convb, bih, bhh, W4ih, W4hh, YS);
    k_heads<<<512,   256, 0, stream>>>(YS, advW, v1W, headacc);
    k_final<<<1,     256, 0, stream>>>(headacc, advb, v1b, v2W, v2b, v3W, v3b, (float*)d_out);
}

// Round 2
// 137.969 us; speedup vs baseline: 3.0235x; 3.0235x over previous
//
#include <hip/hip_runtime.h>
#include <hip/hip_bf16.h>

#define N_NODES 8192
#define FIN 16
#define HD 64
#define E_EDGES 131072
#define S_SEQ 4
#define ROWS 76   // 12 adv + 64 val1
#define NH (N_NODES*HD)   // 524288
#define CHUNKS 128
#define KCH (NH/CHUNKS)   // 4096

__device__ __forceinline__ float dot4(const float4 a, const float4 b) {
    return a.x*b.x + a.y*b.y + a.z*b.z + a.w*b.w;
}

// ---------------- K1: fold edge-MLP into R/Rb, pack GRU weights ------------------
__global__ __launch_bounds__(256) void k_pre(
        const float* __restrict__ w1, const float* __restrict__ b1,
        const float* __restrict__ W2, const float* __restrict__ b2,
        const float* __restrict__ Wih, const float* __restrict__ Whh,
        float* __restrict__ R, float* __restrict__ Rb,
        float* __restrict__ W4ih, float* __restrict__ W4hh) {
    int t = threadIdx.x;
    __shared__ float cw[64], cbs[64];
    if (t < 64) {
        float w = w1[t];
        bool pos = w > 0.f;
        cw[t] = pos ? w : 0.f;
        cbs[t] = pos ? b1[t] : 0.f;   // == 0 for these inputs (b1 = 0)
    }
    __syncthreads();
    for (int i = t; i < 1024; i += 256) {
        float r = 0.f, rb = b2[i];
        for (int j = 0; j < 64; ++j) {
            float w = W2[i*64 + j];
            r  += cw[j]  * w;
            rb += cbs[j] * w;
        }
        R[i] = r; Rb[i] = rb;
    }
    // pack W[gate*64+h][k] -> W4[((kb*3+gate)*64+h)*4 + c], k = kb*4+c
    for (int i = t; i < 12288; i += 256) {
        int kb = i / 768;
        int rem = i % 768;
        int gate = rem / 256;
        int rem2 = rem % 256;
        int h = rem2 / 4;
        int c = rem2 % 4;
        int src = (gate*64 + h)*64 + kb*4 + c;
        W4ih[i] = Wih[src];
        W4hh[i] = Whh[src];
    }
}

// ---------------- K2: per-node precompute S1 = x0@R, S2 = x0@Rb, zero agg -------
__global__ __launch_bounds__(256) void k_node(
        const float* __restrict__ x, const float* __restrict__ R,
        const float* __restrict__ Rb, float* __restrict__ S1,
        float* __restrict__ S2, float* __restrict__ agg) {
    int idx = blockIdx.x*256 + threadIdx.x;    // v*64 + h, over N*H
    int h = idx & 63, v = idx >> 6;
    const float* xv = x + v*FIN;               // s = 0 slice only (matches ref)
    float s1 = 0.f, s2 = 0.f;
#pragma unroll
    for (int f = 0; f < FIN; ++f) {
        float xf = xv[f];
        s1 += xf * R[f*64 + h];
        s2 += xf * Rb[f*64 + h];
    }
    S1[idx] = s1; S2[idx] = s2; agg[idx] = 0.f;
}

// ---------------- K3: edge scatter: agg[dst] += a*S1[src] + S2[src] -------------
__global__ __launch_bounds__(256) void k_edge(
        const int* __restrict__ edge, const float* __restrict__ attr,
        const float* __restrict__ S1, const float* __restrict__ S2,
        float* __restrict__ agg) {
    int idx = blockIdx.x*256 + threadIdx.x;    // [0, E*64)
    int h = idx & 63, e = idx >> 6;
    int src = edge[e];
    int dst = edge[E_EDGES + e];
    float a = attr[e];
    float val = a * S1[src*64 + h] + S2[src*64 + h];
    atomicAdd(&agg[dst*64 + h], val);
}

// ---------------- K4: full 4-step GRU, one kernel, weights in LDS ---------------
__global__ __launch_bounds__(512) void k_gru(
        const float* __restrict__ x, const float* __restrict__ agg,
        const float* __restrict__ h0, const float* __restrict__ rootW,
        const float* __restrict__ convb, const float* __restrict__ bih,
        const float* __restrict__ bhh, const float* __restrict__ W4ih,
        const float* __restrict__ W4hh, float* __restrict__ YS) {
    __shared__ float4 wih[3072];               // 48 KB
    __shared__ float4 whh[3072];               // 48 KB
    __shared__ __align__(16) float xt[32][64]; // 8 KB
    __shared__ __align__(16) float hp[32][64]; // 8 KB
    __shared__ float xraw[32][16];             // 2 KB   (total 114 KB <= 160 KB)
    int tid = threadIdx.x;
    int h = tid & 63, g = tid >> 6;            // g in 0..7, wave-private group
    int v0 = blockIdx.x * 32;

    for (int i = tid; i < 3072; i += 512) {
        wih[i] = ((const float4*)W4ih)[i];
        whh[i] = ((const float4*)W4hh)[i];
    }
    float rw[16];
#pragma unroll
    for (int f = 0; f < 16; ++f) rw[f] = rootW[f*64 + h];
    float cbv = convb[h];
    float br_i = bih[h], bz_i = bih[64+h], bn_i = bih[128+h];
    float br_h = bhh[h], bz_h = bhh[64+h], bn_h = bhh[128+h];
    __syncthreads();

    // init hidden state from h0 (wave-private rows of hp)
#pragma unroll
    for (int n = 0; n < 4; ++n) {
        int node = g*4 + n;
        hp[node][h] = h0[(v0 + node)*64 + h];
    }

    for (int s = 0; s < 4; ++s) {
        // stage raw x for this step; thread layout keeps each wave writing its own rows
        {
            int i = tid >> 4, f = tid & 15;    // wave w writes nodes 4w..4w+3
            xraw[i][f] = x[((s*N_NODES) + v0 + i)*FIN + f];
        }
        // xt = relu(x@rootW + conv_b (+ agg at s==0))
#pragma unroll
        for (int n = 0; n < 4; ++n) {
            int node = g*4 + n;
            float acc = cbv;
#pragma unroll
            for (int f = 0; f < 16; ++f) acc += rw[f] * xraw[node][f];
            if (s == 0) acc += agg[(v0 + node)*64 + h];
            xt[node][h] = fmaxf(acc, 0.f);
        }
        // gates
        float ir[4] = {0,0,0,0}, iz[4] = {0,0,0,0}, in_[4] = {0,0,0,0};
        float hr[4] = {0,0,0,0}, hz[4] = {0,0,0,0}, hn[4] = {0,0,0,0};
        for (int kb = 0; kb < 16; ++kb) {
            float4 wr = wih[(kb*3+0)*64 + h];
            float4 wz = wih[(kb*3+1)*64 + h];
            float4 wn = wih[(kb*3+2)*64 + h];
            float4 ur = whh[(kb*3+0)*64 + h];
            float4 uz = whh[(kb*3+1)*64 + h];
            float4 un = whh[(kb*3+2)*64 + h];
#pragma unroll
            for (int n = 0; n < 4; ++n) {
                int node = g*4 + n;
                const float4 xv = *(const float4*)&xt[node][kb*4];
                const float4 hv = *(const float4*)&hp[node][kb*4];
                ir[n] += dot4(wr, xv);  iz[n] += dot4(wz, xv);  in_[n] += dot4(wn, xv);
                hr[n] += dot4(ur, hv);  hz[n] += dot4(uz, hv);  hn[n] += dot4(un, hv);
            }
        }
#pragma unroll
        for (int n = 0; n < 4; ++n) {
            int node = g*4 + n;
            float hprev = hp[node][h];
            float r = 1.f / (1.f + __expf(-(ir[n] + br_i + hr[n] + br_h)));
            float z = 1.f / (1.f + __expf(-(iz[n] + bz_i + hz[n] + bz_h)));
            float ng = tanhf(in_[n] + bn_i + r * (hn[n] + bn_h));
            float hnew = (1.f - z) * ng + z * hprev;
            hp[node][h] = hnew;
            YS[(s*N_NODES + v0 + node)*64 + h] = hnew;
        }
    }
}

// ---------------- K5: streaming head GEMV -> block partials (no atomics) --------
// grid = 19 row-groups x 128 chunks; each thread: acc[4 rows][4 steps] over its
// 16 K-elements; one wave-reduce at the end; block writes 16 partials.
__global__ __launch_bounds__(256) void k_heads(
        const float* __restrict__ YS, const float* __restrict__ advW,
        const float* __restrict__ v1W, float* __restrict__ partials) {
    int g = blockIdx.x / CHUNKS;               // row-group: rows g*4 .. g*4+3
    int c = blockIdx.x % CHUNKS;               // K chunk
    int t = threadIdx.x;
    const float* W0 = (g < 3) ? (advW + (size_t)(g*4)*NH)
                              : (v1W + (size_t)(g*4 - 12)*NH);
    float acc[4][4];
#pragma unroll
    for (int rr = 0; rr < 4; ++rr)
#pragma unroll
        for (int s = 0; s < 4; ++s) acc[rr][s] = 0.f;

#pragma unroll
    for (int i = 0; i < 4; ++i) {
        int off = c*KCH + i*1024 + t*4;
        float4 y0 = *(const float4*)&YS[0*NH + off];
        float4 y1 = *(const float4*)&YS[1*NH + off];
        float4 y2 = *(const float4*)&YS[2*NH + off];
        float4 y3 = *(const float4*)&YS[3*NH + off];
#pragma unroll
        for (int rr = 0; rr < 4; ++rr) {
            float4 w = *(const float4*)&W0[(size_t)rr*NH + off];
            acc[rr][0] += dot4(w, y0);
            acc[rr][1] += dot4(w, y1);
            acc[rr][2] += dot4(w, y2);
            acc[rr][3] += dot4(w, y3);
        }
    }
    // one wave-level reduce per kernel
#pragma unroll
    for (int rr = 0; rr < 4; ++rr)
#pragma unroll
        for (int s = 0; s < 4; ++s)
#pragma unroll
            for (int off = 32; off > 0; off >>= 1)
                acc[rr][s] += __shfl_down(acc[rr][s], off, 64);

    __shared__ float red[4][16];
    int lane = t & 63, w = t >> 6;
    if (lane == 0) {
#pragma unroll
        for (int rr = 0; rr < 4; ++rr)
#pragma unroll
            for (int s = 0; s < 4; ++s) red[w][rr*4 + s] = acc[rr][s];
    }
    __syncthreads();
    if (t < 16) {
        float v = red[0][t] + red[1][t] + red[2][t] + red[3][t];
        partials[(size_t)(g*CHUNKS + c)*16 + t] = v;
    }
}

// ---------------- K6: reduce partials + tiny tail: val2, val3, dueling ----------
__global__ __launch_bounds__(320) void k_final(
        const float* __restrict__ partials, const float* __restrict__ advb,
        const float* __restrict__ v1b, const float* __restrict__ W2v,
        const float* __restrict__ b2v, const float* __restrict__ W3v,
        const float* __restrict__ b3v, float* __restrict__ out) {
    __shared__ float hacc[ROWS*4];             // 304
    __shared__ float val1[4][64];
    __shared__ float val2[4][64];
    __shared__ float advs[4][12];
    __shared__ float vs[4];
    int t = threadIdx.x;
    if (t < ROWS*4) {
        // t = r*4+s ; r = g*4+rr ; partial index = (g*128+c)*16 + rr*4+s
        int g = t >> 4, low = t & 15;
        float acc = 0.f;
        for (int c = 0; c < CHUNKS; ++c)
            acc += partials[(size_t)(g*CHUNKS + c)*16 + low];
        hacc[t] = acc;
    }
    __syncthreads();
    int s = (t >> 6) & 3, j = t & 63;
    if (t < 256) val1[s][j] = fmaxf(hacc[(12 + j)*4 + s] + v1b[j], 0.f);
    if (t < 48) {
        int ss = t / 12, a = t % 12;
        advs[ss][a] = fmaxf(hacc[a*4 + ss] + advb[a], 0.f);
    }
    __syncthreads();
    if (t < 256) {
        float acc = b2v[j];
        for (int k = 0; k < 64; ++k) acc += W2v[j*64 + k] * val1[s][k];
        val2[s][j] = fmaxf(acc, 0.f);
    }
    __syncthreads();
    if (t < 4) {
        float acc = b3v[0];
        for (int k = 0; k < 64; ++k) acc += W3v[k] * val2[t][k];
        vs[t] = acc;
    }
    __syncthreads();
    if (t < 48) {
        int ss = t / 12, ga = t % 12;
        int grp = ga / 3;
        float m = (advs[ss][grp*3+0] + advs[ss][grp*3+1] + advs[ss][grp*3+2]) * (1.f/3.f);
        out[t] = vs[ss] + advs[ss][ga] - m;
    }
}

extern "C" void kernel_launch(void* const* d_in, const int* in_sizes, int n_in,
                              void* d_out, int out_size, void* d_ws, size_t ws_size,
                              hipStream_t stream) {
    const float* x     = (const float*)d_in[0];
    const int*   edge  = (const int*)  d_in[1];
    const float* attr  = (const float*)d_in[2];
    const float* h0    = (const float*)d_in[3];
    const float* w1    = (const float*)d_in[4];
    const float* b1    = (const float*)d_in[5];
    const float* W2    = (const float*)d_in[6];
    const float* b2    = (const float*)d_in[7];
    const float* rootW = (const float*)d_in[8];
    const float* convb = (const float*)d_in[9];
    const float* Wih   = (const float*)d_in[10];
    const float* Whh   = (const float*)d_in[11];
    const float* bih   = (const float*)d_in[12];
    const float* bhh   = (const float*)d_in[13];
    const float* advW  = (const float*)d_in[14];
    const float* advb  = (const float*)d_in[15];
    const float* v1W   = (const float*)d_in[16];
    const float* v1b   = (const float*)d_in[17];
    const float* v2W   = (const float*)d_in[18];
    const float* v2b   = (const float*)d_in[19];
    const float* v3W   = (const float*)d_in[20];
    const float* v3b   = (const float*)d_in[21];

    float* ws = (float*)d_ws;
    float* R       = ws;                 // 1024
    float* Rb      = ws + 1024;          // 1024
    float* S1      = ws + 2048;          // 524288  (aliased by partials after k_gru)
    float* S2      = ws + 526336;        // 524288
    float* agg     = ws + 1050624;       // 524288
    float* YS      = ws + 1574912;       // 2097152
    float* W4ih    = ws + 3672064;       // 12288
    float* W4hh    = ws + 3684352;       // 12288
    float* partials = S1;                // 19*128*16 = 38912 floats, S1 dead by then

    k_pre  <<<1,     256, 0, stream>>>(w1, b1, W2, b2, Wih, Whh, R, Rb, W4ih, W4hh);
    k_node <<<2048,  256, 0, stream>>>(x, R, Rb, S1, S2, agg);
    k_edge <<<32768, 256, 0, stream>>>(edge, attr, S1, S2, agg);
    k_gru  <<<256,   512, 0, stream>>>(x, agg, h0, rootW, convb, bih, bhh, W4ih, W4hh, YS);
    k_heads<<<19*CHUNKS, 256, 0, stream>>>(YS, advW, v1W, partials);
    k_final<<<1,     320, 0, stream>>>(partials, advb, v1b, v2W, v2b, v3W, v3b, (float*)d_out);
}